// Round 17
// baseline (88.503 us; speedup 1.0000x reference)
//
#include <hip/hip_runtime.h>
#include <hip/hip_bf16.h>
#include <stdint.h>

typedef __attribute__((ext_vector_type(8))) short bf16x8;
typedef __attribute__((ext_vector_type(16))) float f32x16;

#define S_ 16
#define N_ 64
#define D_ 1270
#define F_ 150
#define KP_ 1280
#define FP_ 160
#define NKT 80
#define LOSS_OFF (S_*N_*N_*8)

#define HSTR 172     // hB row stride (bf16)

// ---------- helpers ----------
__device__ inline short f2b(float x) {              // f32 -> bf16 (RNE)
    union { float f; uint32_t u; } v; v.f = x;
    uint32_t r = (v.u + 0x7fffu + ((v.u >> 16) & 1u)) >> 16;
    return (short)r;
}
__device__ inline bf16x8 as_bf16x8(uint4 u) {
    union { uint4 a; bf16x8 b; } c; c.a = u; return c.b;
}

// ---------- fused pack: E -> A-frag, W3/[W1|W2]/Wh/Wout -> B-frag (bf16) ----------
__global__ void k_pack(const float* __restrict__ emb, const float* __restrict__ win,
                       const float* __restrict__ wh, const float* __restrict__ wout,
                       short* __restrict__ eapk, short* __restrict__ w3pk,
                       short* __restrict__ w12pk, short* __restrict__ whpk,
                       short* __restrict__ wopk, float* __restrict__ out) {
    int t = blockIdx.x * 256 + threadIdx.x;
    if (t == 0) out[LOSS_OFF] = 0.f;
    const int TOT_EA = S_ * NKT * 2 * 64;
    const int NW3 = NKT * 5 * 64, NW12 = NKT * 10 * 64, NWH = 10 * 5 * 64, NWO = 10 * 64;
    if (t < TOT_EA) {
        int l  = t & 63;
        int mt = (t >> 6) & 1;
        int kt = (t >> 7) % NKT;
        int s  = t / (NKT * 2 * 64);
        int i  = (l & 31) + mt * 32;
        int k0 = kt * 16 + (l >> 5) * 8;
        const float* src = emb + (size_t)(s * N_ + i) * D_;
        bf16x8 pk;
        if (k0 + 8 <= D_) {
            float2 v0 = *(const float2*)(src + k0);
            float2 v1 = *(const float2*)(src + k0 + 2);
            float2 v2 = *(const float2*)(src + k0 + 4);
            float2 v3 = *(const float2*)(src + k0 + 6);
            pk[0]=f2b(v0.x); pk[1]=f2b(v0.y); pk[2]=f2b(v1.x); pk[3]=f2b(v1.y);
            pk[4]=f2b(v2.x); pk[5]=f2b(v2.y); pk[6]=f2b(v3.x); pk[7]=f2b(v3.y);
        } else {
            #pragma unroll
            for (int u = 0; u < 8; ++u) {
                int k = k0 + u;
                pk[u] = (k < D_) ? f2b(src[k]) : (short)0;
            }
        }
        *(bf16x8*)(eapk + (size_t)t * 8) = pk;
        return;
    }
    int t0 = t - TOT_EA;
    if (t0 < NW3) {
        int l = t0 & 63, nt = (t0 >> 6) % 5, kt = t0 / 320;
        int k0 = kt * 16 + (l >> 5) * 8, f = (l & 31) + nt * 32;
        bf16x8 pk;
        #pragma unroll
        for (int u = 0; u < 8; ++u) {
            int k = k0 + u;
            pk[u] = (k < D_ && f < F_) ? f2b(win[((size_t)(2 * D_) + k) * F_ + f]) : (short)0;
        }
        *(bf16x8*)(w3pk + (size_t)t0 * 8) = pk;
    } else if (t0 < NW3 + NW12) {
        int t2 = t0 - NW3;
        int l = t2 & 63, nt = (t2 >> 6) % 10, kt = t2 / 640;
        int k0 = kt * 16 + (l >> 5) * 8, c = (l & 31) + nt * 32;
        bf16x8 pk;
        #pragma unroll
        for (int u = 0; u < 8; ++u) {
            int k = k0 + u;
            float val = 0.f;
            if (k < D_) {
                if (c < FP_) { if (c < F_) val = win[(size_t)k * F_ + c]; }
                else { int f = c - FP_; if (f < F_) val = win[((size_t)D_ + k) * F_ + f]; }
            }
            pk[u] = f2b(val);
        }
        *(bf16x8*)(w12pk + (size_t)t2 * 8) = pk;
    } else if (t0 < NW3 + NW12 + NWH) {
        int t3 = t0 - NW3 - NW12;
        int l = t3 & 63, nt = (t3 >> 6) % 5, kt = t3 / 320;
        int k0 = kt * 16 + (l >> 5) * 8, f = (l & 31) + nt * 32;
        bf16x8 pk;
        #pragma unroll
        for (int u = 0; u < 8; ++u) {
            int k = k0 + u;
            pk[u] = (k < F_ && f < F_) ? f2b(wh[(size_t)k * F_ + f]) : (short)0;
        }
        *(bf16x8*)(whpk + (size_t)t3 * 8) = pk;
    } else if (t0 < NW3 + NW12 + NWH + NWO) {
        int t4 = t0 - NW3 - NW12 - NWH;
        int l = t4 & 63, kt = t4 >> 6;
        int k0 = kt * 16 + (l >> 5) * 8, f = l & 31;
        bf16x8 pk;
        #pragma unroll
        for (int u = 0; u < 8; ++u) {
            int k = k0 + u;
            pk[u] = (k < F_ && f < 7) ? f2b(wout[k * 7 + f]) : (short)0;
        }
        *(bf16x8*)(wopk + (size_t)t4 * 8) = pk;
    }
}

// ---------- P1 = E@W1 , P2 = E@W2 + b_in : 320 blocks x 2-wave split-K ----------
__global__ __launch_bounds__(128) void k_p12(const short* __restrict__ eapk,
                                             const short* __restrict__ w12pk,
                                             const float* __restrict__ bin,
                                             float* __restrict__ p1, float* __restrict__ p2) {
    __shared__ float red[16][64];
    int bid = blockIdx.x;
    int x = bid & 7, k = bid >> 3;
    int s = x * 2 + (k / 20);
    int rr = k % 20;
    int nt = rr >> 1, mt = rr & 1;
    int lane = threadIdx.x & 63, ks = threadIdx.x >> 6;
    f32x16 acc;
    #pragma unroll
    for (int r = 0; r < 16; ++r) acc[r] = 0.f;
    const size_t abase = (size_t)s * NKT * 2 * 64 * 8;
    #pragma unroll 8
    for (int kt = ks * 40; kt < ks * 40 + 40; ++kt) {
        bf16x8 a = *(const bf16x8*)(eapk + abase + ((size_t)kt * 2 + mt) * 64 * 8 + (size_t)lane * 8);
        bf16x8 b = *(const bf16x8*)(w12pk + ((size_t)(kt * 10 + nt) * 64 + lane) * 8);
        acc = __builtin_amdgcn_mfma_f32_32x32x16_bf16(a, b, acc, 0, 0, 0);
    }
    if (ks == 1) {
        #pragma unroll
        for (int r = 0; r < 16; ++r) red[r][lane] = acc[r];
    }
    __syncthreads();
    if (ks == 0) {
        int c = (lane & 31) + nt * 32;
        #pragma unroll
        for (int r = 0; r < 16; ++r) {
            float v = acc[r] + red[r][lane];
            int i = (r & 3) + 8 * (r >> 2) + 4 * (lane >> 5) + mt * 32;
            if (c < FP_) {
                p1[(size_t)(s * N_ + i) * FP_ + c] = v;
            } else {
                int f = c - FP_;
                float bv = (f < F_) ? bin[f] : 0.f;
                p2[(size_t)(s * N_ + i) * FP_ + f] = v + bv;
            }
        }
    }
}

// ---------- GEMM1 inner loop: 2 j per wave, 40 ktiles (split-K half) ----------
template<int NB>
__device__ __forceinline__ void run_gemm1(const char* ea, const char* w3,
                                          const float* ej0, const float* ej1,
                                          f32x16 (&acc)[2][3]) {
    uint4 euA, euB;
    uint4 bfA[3], bfB[3];
    float4 ejA[4], ejB4[4];

    auto fetch = [&](int kt, uint4& eu, uint4 (&bfv)[3], float4 (&ejr)[4]) {
        eu = *(const uint4*)(ea + (size_t)kt * 2048);
        #pragma unroll
        for (int nb = 0; nb < NB; ++nb)
            bfv[nb] = *(const uint4*)(w3 + (size_t)kt * 5120 + nb * 1024);
        ejr[0] = *(const float4*)(ej0 + kt * 16);
        ejr[1] = *(const float4*)(ej0 + kt * 16 + 4);
        ejr[2] = *(const float4*)(ej1 + kt * 16);
        ejr[3] = *(const float4*)(ej1 + kt * 16 + 4);
    };
    auto step = [&](const uint4& eu, const uint4 (&bfv)[3], const float4 (&ejr)[4]) {
        float ev0[8] = {ejr[0].x,ejr[0].y,ejr[0].z,ejr[0].w,ejr[1].x,ejr[1].y,ejr[1].z,ejr[1].w};
        float ev1[8] = {ejr[2].x,ejr[2].y,ejr[2].z,ejr[2].w,ejr[3].x,ejr[3].y,ejr[3].z,ejr[3].w};
        uint32_t ew[4] = {eu.x, eu.y, eu.z, eu.w};
        union { uint32_t u[4]; bf16x8 v; } av0, av1;
        #pragma unroll
        for (int p = 0; p < 4; ++p) {
            float elo = __uint_as_float(ew[p] << 16);
            float ehi = __uint_as_float(ew[p] & 0xffff0000u);
            float f00 = elo * ev0[2*p], f01 = ehi * ev0[2*p+1];
            float f10 = elo * ev1[2*p], f11 = ehi * ev1[2*p+1];
            uint32_t p0, p1v;
            asm("v_cvt_pk_bf16_f32 %0, %1, %2" : "=v"(p0)  : "v"(f00), "v"(f01));
            asm("v_cvt_pk_bf16_f32 %0, %1, %2" : "=v"(p1v) : "v"(f10), "v"(f11));
            av0.u[p] = p0; av1.u[p] = p1v;
        }
        #pragma unroll
        for (int nb = 0; nb < NB; ++nb) {
            bf16x8 bb = as_bf16x8(bfv[nb]);
            acc[0][nb] = __builtin_amdgcn_mfma_f32_32x32x16_bf16(av0.v, bb, acc[0][nb], 0, 0, 0);
            acc[1][nb] = __builtin_amdgcn_mfma_f32_32x32x16_bf16(av1.v, bb, acc[1][nb], 0, 0, 0);
        }
    };

    fetch(0, euA, bfA, ejA);
    fetch(1, euB, bfB, ejB4);
    #pragma unroll 1
    for (int kt = 0; kt < 40; kt += 2) {
        step(euA, bfA, ejA);
        if (kt + 2 < 40) fetch(kt + 2, euA, bfA, ejA);
        step(euB, bfB, ejB4);
        if (kt + 3 < 40) fetch(kt + 3, euB, bfB, ejB4);
    }
}

// ---------- h writer: ks==0 waves (mt,nh) write both j's ----------
template<int NB, int NT0>
__device__ __forceinline__ void write_h(const f32x16 (&acc)[2][3], short* hB,
                                        const float* p1s, const float* p2r0,
                                        const float* p2r1, int lane, int mt) {
    #pragma unroll
    for (int nb = 0; nb < NB; ++nb) {
        const int f = (lane & 31) + (NT0 + nb) * 32;
        float p1v[16];
        #pragma unroll
        for (int r = 0; r < 16; ++r) {
            int i = (r & 3) + 8 * (r >> 2) + 4 * (lane >> 5) + mt * 32;
            p1v[r] = p1s[(size_t)i * FP_ + f];
        }
        const float p20 = p2r0[f], p21 = p2r1[f];
        #pragma unroll
        for (int r = 0; r < 16; ++r) {
            int i = (r & 3) + 8 * (r >> 2) + 4 * (lane >> 5) + mt * 32;
            hB[i * HSTR + f]             = f2b(acc[0][nb][r] + p1v[r] + p20);
            hB[64 * HSTR + i * HSTR + f] = f2b(acc[1][nb][r] + p1v[r] + p21);
        }
    }
}

// ---------- main fused kernel: block = (s, 2 j's), 8 waves = (ks x mt x nh) ----------
// split-K/2 over waves: each wave's serial K-chain is 40 ktiles (was 80)
__global__ __launch_bounds__(512, 1) void k_main(
    const float* __restrict__ emb, const float* __restrict__ esc,
    const short* __restrict__ eapk, const short* __restrict__ w3pk,
    const short* __restrict__ whpk, const short* __restrict__ wopk,
    const float* __restrict__ p1g, const float* __restrict__ p2g,
    const float* __restrict__ bhv, const float* __restrict__ bout,
    const int* __restrict__ labels, const int* __restrict__ nump,
    float* __restrict__ out) {

    __shared__ char lds[49152];
    float* sbuf = (float*)lds;                 // [2][64][8] f32 scores staging (phase 3)
    float* ejB  = (float*)(lds + 4096);        // GEMM1: [2][1280] f32
    short* hB   = (short*)(lds + 4096);        // phase2: [2][64][HSTR] bf16
    float* red  = (float*)lds;                 // reduction scratch (48 KB, transient)

    const int tid = threadIdx.x, lane = tid & 63, w = tid >> 6;
    const int ks = w & 1, mt = (w >> 1) & 1, nh = w >> 2;
    const int hi8 = (lane >> 5) << 3;
    const int bid = blockIdx.x;
    const int x = bid & 7, kk2 = bid >> 3;
    const int s = x * 2 + (kk2 >> 5);
    const int j0 = (kk2 & 31) * 2;

    // ---- prologue: ej rows (f32, zero-padded) ----
    for (int idx = tid; idx < 2 * KP_; idx += 512) {
        int jr = idx / KP_, k = idx - jr * KP_;
        ejB[idx] = (k < D_) ? emb[(size_t)(s * N_ + j0 + jr) * D_ + k] : 0.f;
    }
    __syncthreads();

    // ---- GEMM1: each wave does its 40-ktile K-half ----
    f32x16 acc[2][3];
    #pragma unroll
    for (int jl = 0; jl < 2; ++jl)
        #pragma unroll
        for (int nb = 0; nb < 3; ++nb)
            #pragma unroll
            for (int r = 0; r < 16; ++r) acc[jl][nb][r] = 0.f;

    {
        const char* ea = (const char*)eapk + (size_t)s * 163840 + (size_t)ks * 40 * 2048
                       + mt * 1024 + lane * 16;
        const char* w3 = (const char*)w3pk + (size_t)ks * 40 * 5120
                       + (nh ? 3 : 0) * 1024 + lane * 16;
        const float* ej0 = ejB + ks * 640 + hi8;
        const float* ej1 = ej0 + KP_;
        if (nh == 0) run_gemm1<3>(ea, w3, ej0, ej1, acc);
        else         run_gemm1<2>(ea, w3, ej0, ej1, acc);
    }
    __syncthreads();   // all GEMM1 done; ejB dead, LDS free for reduction

    // ---- split-K reduction: round A (nh==0 pairs, 48 KB), round B (nh==1, 32 KB) ----
    if (ks == 1 && nh == 0) {
        #pragma unroll
        for (int jl = 0; jl < 2; ++jl)
            #pragma unroll
            for (int nb = 0; nb < 3; ++nb)
                #pragma unroll
                for (int r = 0; r < 16; ++r)
                    red[((mt * 6 + jl * 3 + nb) * 16 + r) * 64 + lane] = acc[jl][nb][r];
    }
    __syncthreads();
    if (ks == 0 && nh == 0) {
        #pragma unroll
        for (int jl = 0; jl < 2; ++jl)
            #pragma unroll
            for (int nb = 0; nb < 3; ++nb)
                #pragma unroll
                for (int r = 0; r < 16; ++r)
                    acc[jl][nb][r] += red[((mt * 6 + jl * 3 + nb) * 16 + r) * 64 + lane];
    }
    __syncthreads();
    if (ks == 1 && nh == 1) {
        #pragma unroll
        for (int jl = 0; jl < 2; ++jl)
            #pragma unroll
            for (int nb = 0; nb < 2; ++nb)
                #pragma unroll
                for (int r = 0; r < 16; ++r)
                    red[((mt * 4 + jl * 2 + nb) * 16 + r) * 64 + lane] = acc[jl][nb][r];
    }
    __syncthreads();
    if (ks == 0 && nh == 1) {
        #pragma unroll
        for (int jl = 0; jl < 2; ++jl)
            #pragma unroll
            for (int nb = 0; nb < 2; ++nb)
                #pragma unroll
                for (int r = 0; r < 16; ++r)
                    acc[jl][nb][r] += red[((mt * 4 + jl * 2 + nb) * 16 + r) * 64 + lane];
    }
    __syncthreads();   // red dead; hB region writable

    // ---- write h for BOTH j's (ks==0 waves only) ----
    if (ks == 0) {
        const float* p1s = p1g + (size_t)(s * N_) * FP_;
        const float* p2r0 = p2g + (size_t)(s * N_ + j0) * FP_;
        const float* p2r1 = p2r0 + FP_;
        if (nh == 0) write_h<3, 0>(acc, hB, p1s, p2r0, p2r1, lane, mt);
        else         write_h<2, 3>(acc, hB, p1s, p2r0, p2r1, lane, mt);
    }
    __syncthreads();

    // ---- GEMM2: h2 = h @ Wh + bh ; 20 tiles (2 jl x 2 mt x 5 nt) over 8 waves ----
    f32x16 acc2[3];
    #pragma unroll
    for (int c = 0; c < 3; ++c)
        #pragma unroll
        for (int r = 0; r < 16; ++r) acc2[c][r] = 0.f;
    #pragma unroll 1
    for (int kt = 0; kt < 10; ++kt) {
        #pragma unroll
        for (int c = 0; c < 3; ++c) {
            int t = w + 8 * c;                 // 0..19
            if (t >= 20) break;
            int jl2 = t / 10, tt = t % 10;
            int mt2 = tt / 5, nt2 = tt % 5;
            const short* ap = hB + jl2 * (64 * HSTR) + ((lane & 31) + mt2 * 32) * HSTR
                            + kt * 16 + hi8;
            short4 alo = *(const short4*)ap;
            short4 ahi = *(const short4*)(ap + 4);
            union { short sh[8]; bf16x8 v; } av;
            av.sh[0] = alo.x; av.sh[1] = alo.y; av.sh[2] = alo.z; av.sh[3] = alo.w;
            av.sh[4] = ahi.x; av.sh[5] = ahi.y; av.sh[6] = ahi.z; av.sh[7] = ahi.w;
            bf16x8 b = *(const bf16x8*)(whpk + ((size_t)(kt * 5 + nt2) * 64 + lane) * 8);
            acc2[c] = __builtin_amdgcn_mfma_f32_32x32x16_bf16(av.v, b, acc2[c], 0, 0, 0);
        }
    }
    __syncthreads();

    // ---- write h2 (bf16) in place of hB; zero pad cols f in [150,160) ----
    #pragma unroll
    for (int c = 0; c < 3; ++c) {
        int t = w + 8 * c;
        if (t >= 20) break;
        int jl2 = t / 10, tt = t % 10;
        int mt2 = tt / 5, nt2 = tt % 5;
        int f = (lane & 31) + nt2 * 32;
        float bhf = (f < F_) ? bhv[f] : 0.f;
        #pragma unroll
        for (int r = 0; r < 16; ++r) {
            int i = (r & 3) + 8 * (r >> 2) + 4 * (lane >> 5) + mt2 * 32;
            short hv = (f < F_) ? f2b(acc2[c][r] + bhf) : (short)0;
            hB[jl2 * (64 * HSTR) + i * HSTR + f] = hv;
        }
    }
    __syncthreads();

    // ---- GEMM3 (MFMA): scores = h2 @ Wout ; 4 tiles (2 jl x 2 mt) on waves 0..3 ----
    if (w < 4) {
        int jl3 = w >> 1, mt3 = w & 1;
        f32x16 acc3;
        #pragma unroll
        for (int r = 0; r < 16; ++r) acc3[r] = 0.f;
        #pragma unroll 1
        for (int kt = 0; kt < 10; ++kt) {
            const short* ap = hB + jl3 * (64 * HSTR) + ((lane & 31) + mt3 * 32) * HSTR
                            + kt * 16 + hi8;
            short4 alo = *(const short4*)ap;
            short4 ahi = *(const short4*)(ap + 4);
            union { short sh[8]; bf16x8 v; } av;
            av.sh[0] = alo.x; av.sh[1] = alo.y; av.sh[2] = alo.z; av.sh[3] = alo.w;
            av.sh[4] = ahi.x; av.sh[5] = ahi.y; av.sh[6] = ahi.z; av.sh[7] = ahi.w;
            bf16x8 b = *(const bf16x8*)(wopk + ((size_t)(kt * 64) + lane) * 8);
            acc3 = __builtin_amdgcn_mfma_f32_32x32x16_bf16(av.v, b, acc3, 0, 0, 0);
        }
        int c3 = lane & 31;
        if (c3 < 7) {
            float bo = bout[c3];
            #pragma unroll
            for (int r = 0; r < 16; ++r) {
                int i = (r & 3) + 8 * (r >> 2) + 4 * (lane >> 5) + mt3 * 32;
                sbuf[jl3 * 512 + i * 8 + c3] = acc3[r] + bo;
            }
        }
    }
    __syncthreads();

    // ---- epilogue: rel_scores write + log-softmax CE + masked loss (128 threads) ----
    if (tid < 128) {
        int jle = tid >> 6;
        int i = tid & 63;
        int j = j0 + jle;
        const float esi = esc[s * N_ + i];
        const float esj = esc[s * N_ + j];
        float rr[8];
        rr[0] = 0.f;
        #pragma unroll
        for (int l = 1; l < 8; ++l) rr[l] = sbuf[jle * 512 + i * 8 + (l - 1)] + esi + esj;

        float4* op = (float4*)(out + ((size_t)(s * N_ + i) * N_ + j) * 8);
        op[0] = make_float4(rr[0], rr[1], rr[2], rr[3]);
        op[1] = make_float4(rr[4], rr[5], rr[6], rr[7]);

        float m = rr[0];
        #pragma unroll
        for (int l = 1; l < 8; ++l) m = fmaxf(m, rr[l]);
        float sum = 0.f;
        #pragma unroll
        for (int l = 0; l < 8; ++l) sum += expf(rr[l] - m);
        const float lse = m + logf(sum);

        const int lab = labels[(s * N_ + i) * N_ + j];
        float ce = lse - rr[lab];
        const int np = nump[s];
        float v = (i < np && j < np) ? ce : 0.f;
        #pragma unroll
        for (int off = 32; off; off >>= 1) v += __shfl_down(v, off);
        if ((tid & 63) == 0) atomicAdd(out + LOSS_OFF, v);
    }
}

extern "C" void kernel_launch(void* const* d_in, const int* in_sizes, int n_in,
                              void* d_out, int out_size, void* d_ws, size_t ws_size,
                              hipStream_t stream) {
    const float* emb    = (const float*)d_in[0];
    const float* esc    = (const float*)d_in[1];
    const float* Win    = (const float*)d_in[2];
    const float* bin    = (const float*)d_in[3];
    const float* Wh     = (const float*)d_in[4];
    const float* bh     = (const float*)d_in[5];
    const float* Wout   = (const float*)d_in[6];
    const float* bout   = (const float*)d_in[7];
    const int*   labels = (const int*)d_in[8];
    const int*   nump   = (const int*)d_in[9];
    float* out = (float*)d_out;

    char* ws = (char*)d_ws;
    short* eapk  = (short*)(ws);                 // 2,621,440 B
    short* w3pk  = (short*)(ws + 2621440);       //   409,600 B
    short* w12pk = (short*)(ws + 3031040);       //   819,200 B
    short* whpk  = (short*)(ws + 3850240);       //    51,200 B
    short* wopk  = (short*)(ws + 3901440);       //    10,240 B
    float* p1    = (float*)(ws + 3911680);       //   655,360 B
    float* p2    = (float*)(ws + 4567040);       //   655,360 B

    const int TOT_EA = S_ * NKT * 2 * 64;
    const int NW = NKT * 5 * 64 + NKT * 10 * 64 + 10 * 5 * 64 + 10 * 64;
    k_pack<<<(TOT_EA + NW + 255) / 256, 256, 0, stream>>>(emb, Win, Wh, Wout,
                                                          eapk, w3pk, w12pk, whpk, wopk, out);
    k_p12<<<320, 128, 0, stream>>>(eapk, w12pk, bin, p1, p2);
    k_main<<<S_ * 32, 512, 0, stream>>>(emb, esc, eapk, w3pk, whpk, wopk, p1, p2,
                                        bh, bout, labels, nump, out);
}

// Round 19
// 84.158 us; speedup vs baseline: 1.0516x; 1.0516x over previous
//
#include <hip/hip_runtime.h>
#include <hip/hip_bf16.h>
#include <stdint.h>

typedef __attribute__((ext_vector_type(8))) short bf16x8;
typedef __attribute__((ext_vector_type(16))) float f32x16;

#define S_ 16
#define N_ 64
#define D_ 1270
#define F_ 150
#define KP_ 1280
#define FP_ 160
#define NKT 80
#define LOSS_OFF (S_*N_*N_*8)

#define HSTR 172     // hB row stride (bf16)

// ---------- helpers ----------
__device__ inline short f2b(float x) {              // f32 -> bf16 (RNE)
    union { float f; uint32_t u; } v; v.f = x;
    uint32_t r = (v.u + 0x7fffu + ((v.u >> 16) & 1u)) >> 16;
    return (short)r;
}
__device__ inline bf16x8 as_bf16x8(uint4 u) {
    union { uint4 a; bf16x8 b; } c; c.a = u; return c.b;
}

// ---------- fused pack: E -> A-frag, W3/[W1|W2]/Wh/Wout -> B-frag (bf16) ----------
__global__ void k_pack(const float* __restrict__ emb, const float* __restrict__ win,
                       const float* __restrict__ wh, const float* __restrict__ wout,
                       short* __restrict__ eapk, short* __restrict__ w3pk,
                       short* __restrict__ w12pk, short* __restrict__ whpk,
                       short* __restrict__ wopk, float* __restrict__ out) {
    int t = blockIdx.x * 256 + threadIdx.x;
    if (t == 0) out[LOSS_OFF] = 0.f;
    const int TOT_EA = S_ * NKT * 2 * 64;
    const int NW3 = NKT * 5 * 64, NW12 = NKT * 10 * 64, NWH = 10 * 5 * 64, NWO = 10 * 64;
    if (t < TOT_EA) {
        int l  = t & 63;
        int mt = (t >> 6) & 1;
        int kt = (t >> 7) % NKT;
        int s  = t / (NKT * 2 * 64);
        int i  = (l & 31) + mt * 32;
        int k0 = kt * 16 + (l >> 5) * 8;
        const float* src = emb + (size_t)(s * N_ + i) * D_;
        bf16x8 pk;
        if (k0 + 8 <= D_) {
            float2 v0 = *(const float2*)(src + k0);
            float2 v1 = *(const float2*)(src + k0 + 2);
            float2 v2 = *(const float2*)(src + k0 + 4);
            float2 v3 = *(const float2*)(src + k0 + 6);
            pk[0]=f2b(v0.x); pk[1]=f2b(v0.y); pk[2]=f2b(v1.x); pk[3]=f2b(v1.y);
            pk[4]=f2b(v2.x); pk[5]=f2b(v2.y); pk[6]=f2b(v3.x); pk[7]=f2b(v3.y);
        } else {
            #pragma unroll
            for (int u = 0; u < 8; ++u) {
                int k = k0 + u;
                pk[u] = (k < D_) ? f2b(src[k]) : (short)0;
            }
        }
        *(bf16x8*)(eapk + (size_t)t * 8) = pk;
        return;
    }
    int t0 = t - TOT_EA;
    if (t0 < NW3) {
        int l = t0 & 63, nt = (t0 >> 6) % 5, kt = t0 / 320;
        int k0 = kt * 16 + (l >> 5) * 8, f = (l & 31) + nt * 32;
        bf16x8 pk;
        #pragma unroll
        for (int u = 0; u < 8; ++u) {
            int k = k0 + u;
            pk[u] = (k < D_ && f < F_) ? f2b(win[((size_t)(2 * D_) + k) * F_ + f]) : (short)0;
        }
        *(bf16x8*)(w3pk + (size_t)t0 * 8) = pk;
    } else if (t0 < NW3 + NW12) {
        int t2 = t0 - NW3;
        int l = t2 & 63, nt = (t2 >> 6) % 10, kt = t2 / 640;
        int k0 = kt * 16 + (l >> 5) * 8, c = (l & 31) + nt * 32;
        bf16x8 pk;
        #pragma unroll
        for (int u = 0; u < 8; ++u) {
            int k = k0 + u;
            float val = 0.f;
            if (k < D_) {
                if (c < FP_) { if (c < F_) val = win[(size_t)k * F_ + c]; }
                else { int f = c - FP_; if (f < F_) val = win[((size_t)D_ + k) * F_ + f]; }
            }
            pk[u] = f2b(val);
        }
        *(bf16x8*)(w12pk + (size_t)t2 * 8) = pk;
    } else if (t0 < NW3 + NW12 + NWH) {
        int t3 = t0 - NW3 - NW12;
        int l = t3 & 63, nt = (t3 >> 6) % 5, kt = t3 / 320;
        int k0 = kt * 16 + (l >> 5) * 8, f = (l & 31) + nt * 32;
        bf16x8 pk;
        #pragma unroll
        for (int u = 0; u < 8; ++u) {
            int k = k0 + u;
            pk[u] = (k < F_ && f < F_) ? f2b(wh[(size_t)k * F_ + f]) : (short)0;
        }
        *(bf16x8*)(whpk + (size_t)t3 * 8) = pk;
    } else if (t0 < NW3 + NW12 + NWH + NWO) {
        int t4 = t0 - NW3 - NW12 - NWH;
        int l = t4 & 63, kt = t4 >> 6;
        int k0 = kt * 16 + (l >> 5) * 8, f = l & 31;
        bf16x8 pk;
        #pragma unroll
        for (int u = 0; u < 8; ++u) {
            int k = k0 + u;
            pk[u] = (k < F_ && f < 7) ? f2b(wout[k * 7 + f]) : (short)0;
        }
        *(bf16x8*)(wopk + (size_t)t4 * 8) = pk;
    }
}

// ---------- P1 = E@W1 , P2 = E@W2 + b_in : 320 blocks x 2-wave split-K ----------
__global__ __launch_bounds__(128) void k_p12(const short* __restrict__ eapk,
                                             const short* __restrict__ w12pk,
                                             const float* __restrict__ bin,
                                             float* __restrict__ p1, float* __restrict__ p2) {
    __shared__ float red[16][64];
    int bid = blockIdx.x;
    int x = bid & 7, k = bid >> 3;
    int s = x * 2 + (k / 20);
    int rr = k % 20;
    int nt = rr >> 1, mt = rr & 1;
    int lane = threadIdx.x & 63, ks = threadIdx.x >> 6;
    f32x16 acc;
    #pragma unroll
    for (int r = 0; r < 16; ++r) acc[r] = 0.f;
    const size_t abase = (size_t)s * NKT * 2 * 64 * 8;
    #pragma unroll 8
    for (int kt = ks * 40; kt < ks * 40 + 40; ++kt) {
        bf16x8 a = *(const bf16x8*)(eapk + abase + ((size_t)kt * 2 + mt) * 64 * 8 + (size_t)lane * 8);
        bf16x8 b = *(const bf16x8*)(w12pk + ((size_t)(kt * 10 + nt) * 64 + lane) * 8);
        acc = __builtin_amdgcn_mfma_f32_32x32x16_bf16(a, b, acc, 0, 0, 0);
    }
    if (ks == 1) {
        #pragma unroll
        for (int r = 0; r < 16; ++r) red[r][lane] = acc[r];
    }
    __syncthreads();
    if (ks == 0) {
        int c = (lane & 31) + nt * 32;
        #pragma unroll
        for (int r = 0; r < 16; ++r) {
            float v = acc[r] + red[r][lane];
            int i = (r & 3) + 8 * (r >> 2) + 4 * (lane >> 5) + mt * 32;
            if (c < FP_) {
                p1[(size_t)(s * N_ + i) * FP_ + c] = v;
            } else {
                int f = c - FP_;
                float bv = (f < F_) ? bin[f] : 0.f;
                p2[(size_t)(s * N_ + i) * FP_ + f] = v + bv;
            }
        }
    }
}

// ---------- GEMM1 inner loop: 1 j per wave, named dbuf incl. ej prefetch ----------
template<int NB>
__device__ __forceinline__ void run_gemm1(const char* ea, const char* w3,
                                          const float* ej0, f32x16 (&acc)[3]) {
    uint4 euA, euB;
    uint4 bfA[3], bfB[3];
    float4 ejA[2], ejB4[2];

    auto fetch = [&](int kt, uint4& eu, uint4 (&bfv)[3], float4 (&ejr)[2]) {
        eu = *(const uint4*)(ea + (size_t)kt * 2048);
        #pragma unroll
        for (int nb = 0; nb < NB; ++nb)
            bfv[nb] = *(const uint4*)(w3 + (size_t)kt * 5120 + nb * 1024);
        ejr[0] = *(const float4*)(ej0 + kt * 16);
        ejr[1] = *(const float4*)(ej0 + kt * 16 + 4);
    };
    auto step = [&](const uint4& eu, const uint4 (&bfv)[3], const float4 (&ejr)[2]) {
        float ev[8] = {ejr[0].x,ejr[0].y,ejr[0].z,ejr[0].w,ejr[1].x,ejr[1].y,ejr[1].z,ejr[1].w};
        uint32_t ew[4] = {eu.x, eu.y, eu.z, eu.w};
        union { uint32_t u[4]; bf16x8 v; } av;
        #pragma unroll
        for (int p = 0; p < 4; ++p) {
            float flo = __uint_as_float(ew[p] << 16) * ev[2 * p];
            float fhi = __uint_as_float(ew[p] & 0xffff0000u) * ev[2 * p + 1];
            uint32_t pk;
            asm("v_cvt_pk_bf16_f32 %0, %1, %2" : "=v"(pk) : "v"(flo), "v"(fhi));
            av.u[p] = pk;
        }
        #pragma unroll
        for (int nb = 0; nb < NB; ++nb)
            acc[nb] = __builtin_amdgcn_mfma_f32_32x32x16_bf16(av.v, as_bf16x8(bfv[nb]), acc[nb], 0, 0, 0);
    };

    fetch(0, euA, bfA, ejA);
    fetch(1, euB, bfB, ejB4);
    #pragma unroll 1
    for (int kt = 0; kt < NKT; kt += 2) {
        step(euA, bfA, ejA);
        if (kt + 2 < NKT) fetch(kt + 2, euA, bfA, ejA);
        step(euB, bfB, ejB4);
        if (kt + 3 < NKT) fetch(kt + 3, euB, bfB, ejB4);
    }
}

// ---------- h writer: wave (jl,mt,nh) writes its own (i-half, f-range) of its j ----------
template<int NB, int NT0>
__device__ __forceinline__ void write_h1(const f32x16 (&acc)[3], short* hBj,
                                         const float* p1s, const float* p2r,
                                         int lane, int mt) {
    #pragma unroll
    for (int nb = 0; nb < NB; ++nb) {
        const int f = (lane & 31) + (NT0 + nb) * 32;
        const float p2v = p2r[f];
        #pragma unroll
        for (int r = 0; r < 16; ++r) {
            int i = (r & 3) + 8 * (r >> 2) + 4 * (lane >> 5) + mt * 32;
            hBj[i * HSTR + f] = f2b(acc[nb][r] + p1s[(size_t)i * FP_ + f] + p2v);
        }
    }
}

// ---------- main fused kernel: block = (s, 2 j's), 8 waves = (jl x mt x nh) ----------
// XCD-swizzled; 512 blocks x 512 threads -> 2 blocks/CU x 8 waves = 4 waves/SIMD
__global__ __launch_bounds__(512, 1) void k_main(
    const float* __restrict__ emb, const float* __restrict__ esc,
    const short* __restrict__ eapk, const short* __restrict__ w3pk,
    const short* __restrict__ whpk, const short* __restrict__ wopk,
    const float* __restrict__ p1g, const float* __restrict__ p2g,
    const float* __restrict__ bhv, const float* __restrict__ bout,
    const int* __restrict__ labels, const int* __restrict__ nump,
    float* __restrict__ out) {

    __shared__ char lds[48128];
    float* sbuf = (float*)lds;                 // [2][64][8] f32 scores staging
    float* ejB  = (float*)(lds + 4096);        // GEMM1: [2][1280] f32
    short* hB   = (short*)(lds + 4096);        // phase2: [2][64][HSTR] bf16 (reused as h2B)

    const int tid = threadIdx.x, lane = tid & 63, w = tid >> 6;
    const int jl = w & 1, mt = (w >> 1) & 1, nh = w >> 2;
    const int hi8 = (lane >> 5) << 3;
    const int bid = blockIdx.x;
    const int x = bid & 7, kk2 = bid >> 3;
    const int s = x * 2 + (kk2 >> 5);
    const int j0 = (kk2 & 31) * 2;

    // ---- prologue: ej rows (f32, zero-padded) ----
    for (int idx = tid; idx < 2 * KP_; idx += 512) {
        int jr = idx / KP_, k = idx - jr * KP_;
        ejB[idx] = (k < D_) ? emb[(size_t)(s * N_ + j0 + jr) * D_ + k] : 0.f;
    }
    __syncthreads();

    // ---- GEMM1: barrier-free, 1 j per wave ----
    f32x16 acc[3];
    #pragma unroll
    for (int nb = 0; nb < 3; ++nb)
        #pragma unroll
        for (int r = 0; r < 16; ++r) acc[nb][r] = 0.f;

    {
        const char* ea = (const char*)eapk + (size_t)s * 163840 + mt * 1024 + lane * 16;
        const char* w3 = (const char*)w3pk + (nh ? 3 : 0) * 1024 + lane * 16;
        const float* ej0 = ejB + jl * KP_ + hi8;
        if (nh == 0) run_gemm1<3>(ea, w3, ej0, acc);
        else         run_gemm1<2>(ea, w3, ej0, acc);
    }
    __syncthreads();   // ejB dead; hB region reusable

    // ---- write h (each wave: its own jl, mt-half, nh f-range) ----
    {
        const float* p1s = p1g + (size_t)(s * N_) * FP_;
        const float* p2r = p2g + (size_t)(s * N_ + j0 + jl) * FP_;
        short* hBj = hB + jl * (64 * HSTR);
        if (nh == 0) write_h1<3, 0>(acc, hBj, p1s, p2r, lane, mt);
        else         write_h1<2, 3>(acc, hBj, p1s, p2r, lane, mt);
    }
    __syncthreads();

    // ---- GEMM2: h2 = h @ Wh + bh ; 20 tiles (2 jl x 2 mt x 5 nt) over 8 waves ----
    f32x16 acc2[3];
    #pragma unroll
    for (int c = 0; c < 3; ++c)
        #pragma unroll
        for (int r = 0; r < 16; ++r) acc2[c][r] = 0.f;
    #pragma unroll 1
    for (int kt = 0; kt < 10; ++kt) {
        #pragma unroll
        for (int c = 0; c < 3; ++c) {
            int t = w + 8 * c;                 // 0..19
            if (t >= 20) break;
            int jl2 = t / 10, tt = t % 10;
            int mt2 = tt / 5, nt2 = tt % 5;
            const short* ap = hB + jl2 * (64 * HSTR) + ((lane & 31) + mt2 * 32) * HSTR
                            + kt * 16 + hi8;
            short4 alo = *(const short4*)ap;
            short4 ahi = *(const short4*)(ap + 4);
            union { short sh[8]; bf16x8 v; } av;
            av.sh[0] = alo.x; av.sh[1] = alo.y; av.sh[2] = alo.z; av.sh[3] = alo.w;
            av.sh[4] = ahi.x; av.sh[5] = ahi.y; av.sh[6] = ahi.z; av.sh[7] = ahi.w;
            bf16x8 b = *(const bf16x8*)(whpk + ((size_t)(kt * 5 + nt2) * 64 + lane) * 8);
            acc2[c] = __builtin_amdgcn_mfma_f32_32x32x16_bf16(av.v, b, acc2[c], 0, 0, 0);
        }
    }
    __syncthreads();

    // ---- write h2 (bf16) in place of hB; zero pad cols f in [150,160) ----
    #pragma unroll
    for (int c = 0; c < 3; ++c) {
        int t = w + 8 * c;
        if (t >= 20) break;
        int jl2 = t / 10, tt = t % 10;
        int mt2 = tt / 5, nt2 = tt % 5;
        int f = (lane & 31) + nt2 * 32;
        float bhf = (f < F_) ? bhv[f] : 0.f;
        #pragma unroll
        for (int r = 0; r < 16; ++r) {
            int i = (r & 3) + 8 * (r >> 2) + 4 * (lane >> 5) + mt2 * 32;
            short hv = (f < F_) ? f2b(acc2[c][r] + bhf) : (short)0;
            hB[jl2 * (64 * HSTR) + i * HSTR + f] = hv;
        }
    }
    __syncthreads();

    // ---- GEMM3 (MFMA): scores = h2 @ Wout ; 4 tiles (2 jl x 2 mt) on waves 0..3 ----
    if (w < 4) {
        int jl3 = w >> 1, mt3 = w & 1;
        f32x16 acc3;
        #pragma unroll
        for (int r = 0; r < 16; ++r) acc3[r] = 0.f;
        #pragma unroll 1
        for (int kt = 0; kt < 10; ++kt) {
            const short* ap = hB + jl3 * (64 * HSTR) + ((lane & 31) + mt3 * 32) * HSTR
                            + kt * 16 + hi8;
            short4 alo = *(const short4*)ap;
            short4 ahi = *(const short4*)(ap + 4);
            union { short sh[8]; bf16x8 v; } av;
            av.sh[0] = alo.x; av.sh[1] = alo.y; av.sh[2] = alo.z; av.sh[3] = alo.w;
            av.sh[4] = ahi.x; av.sh[5] = ahi.y; av.sh[6] = ahi.z; av.sh[7] = ahi.w;
            bf16x8 b = *(const bf16x8*)(wopk + ((size_t)(kt * 64) + lane) * 8);
            acc3 = __builtin_amdgcn_mfma_f32_32x32x16_bf16(av.v, b, acc3, 0, 0, 0);
        }
        int c3 = lane & 31;
        if (c3 < 7) {
            float bo = bout[c3];
            #pragma unroll
            for (int r = 0; r < 16; ++r) {
                int i = (r & 3) + 8 * (r >> 2) + 4 * (lane >> 5) + mt3 * 32;
                sbuf[jl3 * 512 + i * 8 + c3] = acc3[r] + bo;
            }
        }
    }
    __syncthreads();

    // ---- epilogue: rel_scores write + log-softmax CE + masked loss (128 threads) ----
    if (tid < 128) {
        int jle = tid >> 6;
        int i = tid & 63;
        int j = j0 + jle;
        const float esi = esc[s * N_ + i];
        const float esj = esc[s * N_ + j];
        float rr[8];
        rr[0] = 0.f;
        #pragma unroll
        for (int l = 1; l < 8; ++l) rr[l] = sbuf[jle * 512 + i * 8 + (l - 1)] + esi + esj;

        float4* op = (float4*)(out + ((size_t)(s * N_ + i) * N_ + j) * 8);
        op[0] = make_float4(rr[0], rr[1], rr[2], rr[3]);
        op[1] = make_float4(rr[4], rr[5], rr[6], rr[7]);

        float m = rr[0];
        #pragma unroll
        for (int l = 1; l < 8; ++l) m = fmaxf(m, rr[l]);
        float sum = 0.f;
        #pragma unroll
        for (int l = 0; l < 8; ++l) sum += expf(rr[l] - m);
        const float lse = m + logf(sum);

        const int lab = labels[(s * N_ + i) * N_ + j];
        float ce = lse - rr[lab];
        const int np = nump[s];
        float v = (i < np && j < np) ? ce : 0.f;
        #pragma unroll
        for (int off = 32; off; off >>= 1) v += __shfl_down(v, off);
        if ((tid & 63) == 0) atomicAdd(out + LOSS_OFF, v);
    }
}

extern "C" void kernel_launch(void* const* d_in, const int* in_sizes, int n_in,
                              void* d_out, int out_size, void* d_ws, size_t ws_size,
                              hipStream_t stream) {
    const float* emb    = (const float*)d_in[0];
    const float* esc    = (const float*)d_in[1];
    const float* Win    = (const float*)d_in[2];
    const float* bin    = (const float*)d_in[3];
    const float* Wh     = (const float*)d_in[4];
    const float* bh     = (const float*)d_in[5];
    const float* Wout   = (const float*)d_in[6];
    const float* bout   = (const float*)d_in[7];
    const int*   labels = (const int*)d_in[8];
    const int*   nump   = (const int*)d_in[9];
    float* out = (float*)d_out;

    char* ws = (char*)d_ws;
    short* eapk  = (short*)(ws);                 // 2,621,440 B
    short* w3pk  = (short*)(ws + 2621440);       //   409,600 B
    short* w12pk = (short*)(ws + 3031040);       //   819,200 B
    short* whpk  = (short*)(ws + 3850240);       //    51,200 B
    short* wopk  = (short*)(ws + 3901440);       //    10,240 B
    float* p1    = (float*)(ws + 3911680);       //   655,360 B
    float* p2    = (float*)(ws + 4567040);       //   655,360 B

    const int TOT_EA = S_ * NKT * 2 * 64;
    const int NW = NKT * 5 * 64 + NKT * 10 * 64 + 10 * 5 * 64 + 10 * 64;
    k_pack<<<(TOT_EA + NW + 255) / 256, 256, 0, stream>>>(emb, Win, Wh, Wout,
                                                          eapk, w3pk, w12pk, whpk, wopk, out);
    k_p12<<<320, 128, 0, stream>>>(eapk, w12pk, bin, p1, p2);
    k_main<<<S_ * 32, 512, 0, stream>>>(emb, esc, eapk, w3pk, whpk, wopk, p1, p2,
                                        bh, bout, labels, nump, out);
}

// Round 20
// 81.007 us; speedup vs baseline: 1.0925x; 1.0389x over previous
//
#include <hip/hip_runtime.h>
#include <hip/hip_bf16.h>
#include <stdint.h>

typedef __attribute__((ext_vector_type(8))) short bf16x8;
typedef __attribute__((ext_vector_type(16))) float f32x16;

#define S_ 16
#define N_ 64
#define D_ 1270
#define F_ 150
#define KP_ 1280
#define FP_ 160
#define NKT 80
#define LOSS_OFF (S_*N_*N_*8)

#define HSTR 172     // hB row stride (bf16)
#define STGB 28672   // staging bytes per superstep: EA 8 KB + W3 20 KB

// ---------- helpers ----------
__device__ inline short f2b(float x) {              // f32 -> bf16 (RNE)
    union { float f; uint32_t u; } v; v.f = x;
    uint32_t r = (v.u + 0x7fffu + ((v.u >> 16) & 1u)) >> 16;
    return (short)r;
}
__device__ inline bf16x8 as_bf16x8(uint4 u) {
    union { uint4 a; bf16x8 b; } c; c.a = u; return c.b;
}

// ---------- fused pack: E -> A-frag, W3/[W1|W2]/Wh/Wout -> B-frag (bf16) ----------
__global__ void k_pack(const float* __restrict__ emb, const float* __restrict__ win,
                       const float* __restrict__ wh, const float* __restrict__ wout,
                       short* __restrict__ eapk, short* __restrict__ w3pk,
                       short* __restrict__ w12pk, short* __restrict__ whpk,
                       short* __restrict__ wopk, float* __restrict__ out) {
    int t = blockIdx.x * 256 + threadIdx.x;
    if (t == 0) out[LOSS_OFF] = 0.f;
    const int TOT_EA = S_ * NKT * 2 * 64;
    const int NW3 = NKT * 5 * 64, NW12 = NKT * 10 * 64, NWH = 10 * 5 * 64, NWO = 10 * 64;
    if (t < TOT_EA) {
        int l  = t & 63;
        int mt = (t >> 6) & 1;
        int kt = (t >> 7) % NKT;
        int s  = t / (NKT * 2 * 64);
        int i  = (l & 31) + mt * 32;
        int k0 = kt * 16 + (l >> 5) * 8;
        const float* src = emb + (size_t)(s * N_ + i) * D_;
        bf16x8 pk;
        if (k0 + 8 <= D_) {
            float2 v0 = *(const float2*)(src + k0);
            float2 v1 = *(const float2*)(src + k0 + 2);
            float2 v2 = *(const float2*)(src + k0 + 4);
            float2 v3 = *(const float2*)(src + k0 + 6);
            pk[0]=f2b(v0.x); pk[1]=f2b(v0.y); pk[2]=f2b(v1.x); pk[3]=f2b(v1.y);
            pk[4]=f2b(v2.x); pk[5]=f2b(v2.y); pk[6]=f2b(v3.x); pk[7]=f2b(v3.y);
        } else {
            #pragma unroll
            for (int u = 0; u < 8; ++u) {
                int k = k0 + u;
                pk[u] = (k < D_) ? f2b(src[k]) : (short)0;
            }
        }
        *(bf16x8*)(eapk + (size_t)t * 8) = pk;
        return;
    }
    int t0 = t - TOT_EA;
    if (t0 < NW3) {
        int l = t0 & 63, nt = (t0 >> 6) % 5, kt = t0 / 320;
        int k0 = kt * 16 + (l >> 5) * 8, f = (l & 31) + nt * 32;
        bf16x8 pk;
        #pragma unroll
        for (int u = 0; u < 8; ++u) {
            int k = k0 + u;
            pk[u] = (k < D_ && f < F_) ? f2b(win[((size_t)(2 * D_) + k) * F_ + f]) : (short)0;
        }
        *(bf16x8*)(w3pk + (size_t)t0 * 8) = pk;
    } else if (t0 < NW3 + NW12) {
        int t2 = t0 - NW3;
        int l = t2 & 63, nt = (t2 >> 6) % 10, kt = t2 / 640;
        int k0 = kt * 16 + (l >> 5) * 8, c = (l & 31) + nt * 32;
        bf16x8 pk;
        #pragma unroll
        for (int u = 0; u < 8; ++u) {
            int k = k0 + u;
            float val = 0.f;
            if (k < D_) {
                if (c < FP_) { if (c < F_) val = win[(size_t)k * F_ + c]; }
                else { int f = c - FP_; if (f < F_) val = win[((size_t)D_ + k) * F_ + f]; }
            }
            pk[u] = f2b(val);
        }
        *(bf16x8*)(w12pk + (size_t)t2 * 8) = pk;
    } else if (t0 < NW3 + NW12 + NWH) {
        int t3 = t0 - NW3 - NW12;
        int l = t3 & 63, nt = (t3 >> 6) % 5, kt = t3 / 320;
        int k0 = kt * 16 + (l >> 5) * 8, f = (l & 31) + nt * 32;
        bf16x8 pk;
        #pragma unroll
        for (int u = 0; u < 8; ++u) {
            int k = k0 + u;
            pk[u] = (k < F_ && f < F_) ? f2b(wh[(size_t)k * F_ + f]) : (short)0;
        }
        *(bf16x8*)(whpk + (size_t)t3 * 8) = pk;
    } else if (t0 < NW3 + NW12 + NWH + NWO) {
        int t4 = t0 - NW3 - NW12 - NWH;
        int l = t4 & 63, kt = t4 >> 6;
        int k0 = kt * 16 + (l >> 5) * 8, f = l & 31;
        bf16x8 pk;
        #pragma unroll
        for (int u = 0; u < 8; ++u) {
            int k = k0 + u;
            pk[u] = (k < F_ && f < 7) ? f2b(wout[k * 7 + f]) : (short)0;
        }
        *(bf16x8*)(wopk + (size_t)t4 * 8) = pk;
    }
}

// ---------- P1 = E@W1 , P2 = E@W2 + b_in : 320 blocks x 2-wave split-K ----------
__global__ __launch_bounds__(128) void k_p12(const short* __restrict__ eapk,
                                             const short* __restrict__ w12pk,
                                             const float* __restrict__ bin,
                                             float* __restrict__ p1, float* __restrict__ p2) {
    __shared__ float red[16][64];
    int bid = blockIdx.x;
    int x = bid & 7, k = bid >> 3;
    int s = x * 2 + (k / 20);
    int rr = k % 20;
    int nt = rr >> 1, mt = rr & 1;
    int lane = threadIdx.x & 63, ks = threadIdx.x >> 6;
    f32x16 acc;
    #pragma unroll
    for (int r = 0; r < 16; ++r) acc[r] = 0.f;
    const size_t abase = (size_t)s * NKT * 2 * 64 * 8;
    #pragma unroll 8
    for (int kt = ks * 40; kt < ks * 40 + 40; ++kt) {
        bf16x8 a = *(const bf16x8*)(eapk + abase + ((size_t)kt * 2 + mt) * 64 * 8 + (size_t)lane * 8);
        bf16x8 b = *(const bf16x8*)(w12pk + ((size_t)(kt * 10 + nt) * 64 + lane) * 8);
        acc = __builtin_amdgcn_mfma_f32_32x32x16_bf16(a, b, acc, 0, 0, 0);
    }
    if (ks == 1) {
        #pragma unroll
        for (int r = 0; r < 16; ++r) red[r][lane] = acc[r];
    }
    __syncthreads();
    if (ks == 0) {
        int c = (lane & 31) + nt * 32;
        #pragma unroll
        for (int r = 0; r < 16; ++r) {
            float v = acc[r] + red[r][lane];
            int i = (r & 3) + 8 * (r >> 2) + 4 * (lane >> 5) + mt * 32;
            if (c < FP_) {
                p1[(size_t)(s * N_ + i) * FP_ + c] = v;
            } else {
                int f = c - FP_;
                float bv = (f < F_) ? bin[f] : 0.f;
                p2[(size_t)(s * N_ + i) * FP_ + f] = v + bv;
            }
        }
    }
}

// ---------- h writer: wave (jl,mt,nh) writes its own (i-half, f-range) of its j ----------
template<int NB, int NT0>
__device__ __forceinline__ void write_h1(const f32x16 (&acc)[3], short* hBj,
                                         const float* p1s, const float* p2r,
                                         int lane, int mt) {
    #pragma unroll
    for (int nb = 0; nb < NB; ++nb) {
        const int f = (lane & 31) + (NT0 + nb) * 32;
        const float p2v = p2r[f];
        #pragma unroll
        for (int r = 0; r < 16; ++r) {
            int i = (r & 3) + 8 * (r >> 2) + 4 * (lane >> 5) + mt * 32;
            hBj[i * HSTR + f] = f2b(acc[nb][r] + p1s[(size_t)i * FP_ + f] + p2v);
        }
    }
}

// ---------- main fused kernel: block = (s, 2 j's), 8 waves = (jl x mt x nh) ----------
// GEMM1: fragments staged block-wide into LDS (global_load_lds) to cut L1 traffic;
// all 8 waves feed from the LDS pipe. 2 blocks/CU x 8 waves = 4 waves/SIMD.
__global__ __launch_bounds__(512, 1) void k_main(
    const float* __restrict__ emb, const float* __restrict__ esc,
    const short* __restrict__ eapk, const short* __restrict__ w3pk,
    const short* __restrict__ whpk, const short* __restrict__ wopk,
    const float* __restrict__ p1g, const float* __restrict__ p2g,
    const float* __restrict__ bhv, const float* __restrict__ bout,
    const int* __restrict__ labels, const int* __restrict__ nump,
    float* __restrict__ out) {

    __shared__ char lds[67584];
    float* ejB  = (float*)lds;                 // GEMM1: [2][1280] f32 (10240 B)
    char*  stg  = lds + 10240;                 // GEMM1: 2 x STGB (57344 B)
    short* hB   = (short*)lds;                 // phase2: [2][64][HSTR] bf16 (44032 B)
    float* sbuf = (float*)(lds + 44032);       // phase2: [2][64][8] f32 (4096 B)

    const int tid = threadIdx.x, lane = tid & 63, w = tid >> 6;
    const int jl = w & 1, mt = (w >> 1) & 1, nh = w >> 2;
    const int hi8 = (lane >> 5) << 3;
    const int bid = blockIdx.x;
    const int x = bid & 7, kk2 = bid >> 3;
    const int s = x * 2 + (kk2 >> 5);
    const int j0 = (kk2 & 31) * 2;

    const char* easrc = (const char*)eapk + (size_t)s * 163840;
    const char* w3src = (const char*)w3pk;

    // ---- prologue: ej rows (f32, zero-padded) ----
    for (int idx = tid; idx < 2 * KP_; idx += 512) {
        int jr = idx / KP_, k = idx - jr * KP_;
        ejB[idx] = (k < D_) ? emb[(size_t)(s * N_ + j0 + jr) * D_ + k] : 0.f;
    }

    // stage superstep 0 (28 x 1KB slices over 8 waves)
    {
        const char* ea = easrc;
        const char* w3 = w3src;
        #pragma unroll
        for (int q = 0; q < 4; ++q) {
            int n = w + 8 * q;
            if (n < 28) {
                const char* src = (n < 8) ? (ea + (n << 10)) : (w3 + ((n - 8) << 10));
                __builtin_amdgcn_global_load_lds(
                    (const __attribute__((address_space(1))) void*)(src + (lane << 4)),
                    (__attribute__((address_space(3))) void*)(stg + (n << 10) + (lane << 4)),
                    16, 0, 0);
            }
        }
    }
    __syncthreads();

    // ---- GEMM1: 20 supersteps x 4 ktiles; double-buffered LDS staging ----
    f32x16 acc[3];
    #pragma unroll
    for (int nb = 0; nb < 3; ++nb)
        #pragma unroll
        for (int r = 0; r < 16; ++r) acc[nb][r] = 0.f;

    const float* ejp = ejB + jl * KP_ + hi8;
    const int NT0v = nh ? 3 : 0;
    const int NBv  = nh ? 2 : 3;

    #pragma unroll 1
    for (int ss = 0; ss < 20; ++ss) {
        const int cur = ss & 1;
        if (ss < 19) {                          // issue next-superstep DMA before compute
            const char* ea = easrc + (size_t)(ss + 1) * 8192;
            const char* w3 = w3src + (size_t)(ss + 1) * 20480;
            char* dst = stg + (cur ^ 1) * STGB;
            #pragma unroll
            for (int q = 0; q < 4; ++q) {
                int n = w + 8 * q;
                if (n < 28) {
                    const char* src = (n < 8) ? (ea + (n << 10)) : (w3 + ((n - 8) << 10));
                    __builtin_amdgcn_global_load_lds(
                        (const __attribute__((address_space(1))) void*)(src + (lane << 4)),
                        (__attribute__((address_space(3))) void*)(dst + (n << 10) + (lane << 4)),
                        16, 0, 0);
                }
            }
        }
        const char* bb = stg + cur * STGB;
        #pragma unroll
        for (int kk = 0; kk < 4; ++kk) {
            const int kt = ss * 4 + kk;
            uint4 eu = *(const uint4*)(bb + kk * 2048 + mt * 1024 + (lane << 4));
            float4 e0 = *(const float4*)(ejp + kt * 16);
            float4 e1 = *(const float4*)(ejp + kt * 16 + 4);
            float ev[8] = {e0.x,e0.y,e0.z,e0.w,e1.x,e1.y,e1.z,e1.w};
            uint32_t ew[4] = {eu.x, eu.y, eu.z, eu.w};
            union { uint32_t u[4]; bf16x8 v; } av;
            #pragma unroll
            for (int p = 0; p < 4; ++p) {
                float flo = __uint_as_float(ew[p] << 16) * ev[2 * p];
                float fhi = __uint_as_float(ew[p] & 0xffff0000u) * ev[2 * p + 1];
                uint32_t pk;
                asm("v_cvt_pk_bf16_f32 %0, %1, %2" : "=v"(pk) : "v"(flo), "v"(fhi));
                av.u[p] = pk;
            }
            #pragma unroll
            for (int nb = 0; nb < 3; ++nb) {
                if (nb < NBv) {
                    bf16x8 b8 = *(const bf16x8*)(bb + 8192 + kk * 5120 + (NT0v + nb) * 1024 + (lane << 4));
                    acc[nb] = __builtin_amdgcn_mfma_f32_32x32x16_bf16(av.v, b8, acc[nb], 0, 0, 0);
                }
            }
        }
        __syncthreads();                        // drains prefetch DMA (issued a superstep ago)
    }

    // ---- write h (each wave: its own jl, mt-half, nh f-range) ----
    {
        const float* p1s = p1g + (size_t)(s * N_) * FP_;
        const float* p2r = p2g + (size_t)(s * N_ + j0 + jl) * FP_;
        short* hBj = hB + jl * (64 * HSTR);
        if (nh == 0) write_h1<3, 0>(acc, hBj, p1s, p2r, lane, mt);
        else         write_h1<2, 3>(acc, hBj, p1s, p2r, lane, mt);
    }
    __syncthreads();

    // ---- GEMM2: h2 = h @ Wh + bh ; 20 tiles (2 jl x 2 mt x 5 nt) over 8 waves ----
    f32x16 acc2[3];
    #pragma unroll
    for (int c = 0; c < 3; ++c)
        #pragma unroll
        for (int r = 0; r < 16; ++r) acc2[c][r] = 0.f;
    #pragma unroll 1
    for (int kt = 0; kt < 10; ++kt) {
        #pragma unroll
        for (int c = 0; c < 3; ++c) {
            int t = w + 8 * c;                 // 0..19
            if (t >= 20) break;
            int jl2 = t / 10, tt = t % 10;
            int mt2 = tt / 5, nt2 = tt % 5;
            const short* ap = hB + jl2 * (64 * HSTR) + ((lane & 31) + mt2 * 32) * HSTR
                            + kt * 16 + hi8;
            short4 alo = *(const short4*)ap;
            short4 ahi = *(const short4*)(ap + 4);
            union { short sh[8]; bf16x8 v; } av;
            av.sh[0] = alo.x; av.sh[1] = alo.y; av.sh[2] = alo.z; av.sh[3] = alo.w;
            av.sh[4] = ahi.x; av.sh[5] = ahi.y; av.sh[6] = ahi.z; av.sh[7] = ahi.w;
            bf16x8 b = *(const bf16x8*)(whpk + ((size_t)(kt * 5 + nt2) * 64 + lane) * 8);
            acc2[c] = __builtin_amdgcn_mfma_f32_32x32x16_bf16(av.v, b, acc2[c], 0, 0, 0);
        }
    }
    __syncthreads();

    // ---- write h2 (bf16) in place of hB; zero pad cols f in [150,160) ----
    #pragma unroll
    for (int c = 0; c < 3; ++c) {
        int t = w + 8 * c;
        if (t >= 20) break;
        int jl2 = t / 10, tt = t % 10;
        int mt2 = tt / 5, nt2 = tt % 5;
        int f = (lane & 31) + nt2 * 32;
        float bhf = (f < F_) ? bhv[f] : 0.f;
        #pragma unroll
        for (int r = 0; r < 16; ++r) {
            int i = (r & 3) + 8 * (r >> 2) + 4 * (lane >> 5) + mt2 * 32;
            short hv = (f < F_) ? f2b(acc2[c][r] + bhf) : (short)0;
            hB[jl2 * (64 * HSTR) + i * HSTR + f] = hv;
        }
    }
    __syncthreads();

    // ---- GEMM3 (MFMA): scores = h2 @ Wout ; 4 tiles (2 jl x 2 mt) on waves 0..3 ----
    if (w < 4) {
        int jl3 = w >> 1, mt3 = w & 1;
        f32x16 acc3;
        #pragma unroll
        for (int r = 0; r < 16; ++r) acc3[r] = 0.f;
        #pragma unroll 1
        for (int kt = 0; kt < 10; ++kt) {
            const short* ap = hB + jl3 * (64 * HSTR) + ((lane & 31) + mt3 * 32) * HSTR
                            + kt * 16 + hi8;
            short4 alo = *(const short4*)ap;
            short4 ahi = *(const short4*)(ap + 4);
            union { short sh[8]; bf16x8 v; } av;
            av.sh[0] = alo.x; av.sh[1] = alo.y; av.sh[2] = alo.z; av.sh[3] = alo.w;
            av.sh[4] = ahi.x; av.sh[5] = ahi.y; av.sh[6] = ahi.z; av.sh[7] = ahi.w;
            bf16x8 b = *(const bf16x8*)(wopk + ((size_t)(kt * 64) + lane) * 8);
            acc3 = __builtin_amdgcn_mfma_f32_32x32x16_bf16(av.v, b, acc3, 0, 0, 0);
        }
        int c3 = lane & 31;
        if (c3 < 7) {
            float bo = bout[c3];
            #pragma unroll
            for (int r = 0; r < 16; ++r) {
                int i = (r & 3) + 8 * (r >> 2) + 4 * (lane >> 5) + mt3 * 32;
                sbuf[jl3 * 512 + i * 8 + c3] = acc3[r] + bo;
            }
        }
    }
    __syncthreads();

    // ---- epilogue: rel_scores write + log-softmax CE + masked loss (128 threads) ----
    if (tid < 128) {
        int jle = tid >> 6;
        int i = tid & 63;
        int j = j0 + jle;
        const float esi = esc[s * N_ + i];
        const float esj = esc[s * N_ + j];
        float rr[8];
        rr[0] = 0.f;
        #pragma unroll
        for (int l = 1; l < 8; ++l) rr[l] = sbuf[jle * 512 + i * 8 + (l - 1)] + esi + esj;

        float4* op = (float4*)(out + ((size_t)(s * N_ + i) * N_ + j) * 8);
        op[0] = make_float4(rr[0], rr[1], rr[2], rr[3]);
        op[1] = make_float4(rr[4], rr[5], rr[6], rr[7]);

        float m = rr[0];
        #pragma unroll
        for (int l = 1; l < 8; ++l) m = fmaxf(m, rr[l]);
        float sum = 0.f;
        #pragma unroll
        for (int l = 0; l < 8; ++l) sum += expf(rr[l] - m);
        const float lse = m + logf(sum);

        const int lab = labels[(s * N_ + i) * N_ + j];
        float ce = lse - rr[lab];
        const int np = nump[s];
        float v = (i < np && j < np) ? ce : 0.f;
        #pragma unroll
        for (int off = 32; off; off >>= 1) v += __shfl_down(v, off);
        if ((tid & 63) == 0) atomicAdd(out + LOSS_OFF, v);
    }
}

extern "C" void kernel_launch(void* const* d_in, const int* in_sizes, int n_in,
                              void* d_out, int out_size, void* d_ws, size_t ws_size,
                              hipStream_t stream) {
    const float* emb    = (const float*)d_in[0];
    const float* esc    = (const float*)d_in[1];
    const float* Win    = (const float*)d_in[2];
    const float* bin    = (const float*)d_in[3];
    const float* Wh     = (const float*)d_in[4];
    const float* bh     = (const float*)d_in[5];
    const float* Wout   = (const float*)d_in[6];
    const float* bout   = (const float*)d_in[7];
    const int*   labels = (const int*)d_in[8];
    const int*   nump   = (const int*)d_in[9];
    float* out = (float*)d_out;

    char* ws = (char*)d_ws;
    short* eapk  = (short*)(ws);                 // 2,621,440 B
    short* w3pk  = (short*)(ws + 2621440);       //   409,600 B
    short* w12pk = (short*)(ws + 3031040);       //   819,200 B
    short* whpk  = (short*)(ws + 3850240);       //    51,200 B
    short* wopk  = (short*)(ws + 3901440);       //    10,240 B
    float* p1    = (float*)(ws + 3911680);       //   655,360 B
    float* p2    = (float*)(ws + 4567040);       //   655,360 B

    const int TOT_EA = S_ * NKT * 2 * 64;
    const int NW = NKT * 5 * 64 + NKT * 10 * 64 + 10 * 5 * 64 + 10 * 64;
    k_pack<<<(TOT_EA + NW + 255) / 256, 256, 0, stream>>>(emb, Win, Wh, Wout,
                                                          eapk, w3pk, w12pk, whpk, wopk, out);
    k_p12<<<320, 128, 0, stream>>>(eapk, w12pk, bin, p1, p2);
    k_main<<<S_ * 32, 512, 0, stream>>>(emb, esc, eapk, w3pk, whpk, wopk, p1, p2,
                                        bh, bout, labels, nump, out);
}